// Round 1
// baseline (31027.393 us; speedup 1.0000x reference)
//
#include <hip/hip_runtime.h>

#define B_    1024
#define H_    1024
#define G4_   4096
#define FEAT_ 75
#define KTOT  (H_ + FEAT_)   // 1099: virtual concatenated K (h then x)

// d_out layout (floats): [future_pose | comp_pose | comp_vel]
#define OFF_CP 1920000UL           // 1024*25*75
#define OFF_CV 5760000UL           // OFF_CP + 1024*50*75

__device__ __forceinline__ float sigmoidf_(float x) {
    return 1.0f / (1.0f + __expf(-x));
}

// ---------------------------------------------------------------------------
// Fused gates GEMM: gates[b,g] = sum_k h[b,k]*Whh[g,k] + sum_f x[b,f]*Wih[g,f]
//                              + bih[g] + bhh[g]
// A (inputs) and W (weights) are both K-contiguous (A@B^T form).
// 64x64 tile, BK=32, 256 threads, 4x4 acc/thread. K tiles 0..31 hit the fast
// float4 path (h region, 1024 % 32 == 0); tiles 32..34 cover the x region
// with predicated scalar loads (xk < 75, else 0).
// ---------------------------------------------------------------------------
#define BM 64
#define BN 64
#define BK 32

__global__ __launch_bounds__(256)
void gates_gemm_kernel(const float* __restrict__ hbuf,
                       const float* __restrict__ xbuf, int x_stride,
                       const float* __restrict__ Whh,
                       const float* __restrict__ Wih,
                       const float* __restrict__ bih,
                       const float* __restrict__ bhh,
                       float* __restrict__ gates)
{
    __shared__ float As[BM][BK + 1];  // +1 pad: kills 16-way bank conflict
    __shared__ float Bs[BN][BK + 1];

    const int tid  = threadIdx.x;
    const int tx   = tid & 15;        // col group (0..15)
    const int ty   = tid >> 4;        // row group (0..15)
    const int row0 = blockIdx.y * BM; // batch tile
    const int col0 = blockIdx.x * BN; // gate-col tile
    const int lr   = tid >> 2;        // loader row 0..63
    const int lc   = (tid & 3) * 8;   // loader col {0,8,16,24}

    float acc[4][4] = {};

    const int nkt = (KTOT + BK - 1) / BK;  // 35
    for (int kt = 0; kt < nkt; ++kt) {
        const int k0 = kt * BK;
        const int gk = k0 + lc;

        if (gk + 8 <= H_) {  // fast path: fully inside h / Whh region
            const float* pa = hbuf + (size_t)(row0 + lr) * H_ + gk;
            float4 a0 = *(const float4*)pa;
            float4 a1 = *(const float4*)(pa + 4);
            As[lr][lc+0]=a0.x; As[lr][lc+1]=a0.y; As[lr][lc+2]=a0.z; As[lr][lc+3]=a0.w;
            As[lr][lc+4]=a1.x; As[lr][lc+5]=a1.y; As[lr][lc+6]=a1.z; As[lr][lc+7]=a1.w;

            const float* pb = Whh + (size_t)(col0 + lr) * H_ + gk;
            float4 b0 = *(const float4*)pb;
            float4 b1 = *(const float4*)(pb + 4);
            Bs[lr][lc+0]=b0.x; Bs[lr][lc+1]=b0.y; Bs[lr][lc+2]=b0.z; Bs[lr][lc+3]=b0.w;
            Bs[lr][lc+4]=b1.x; Bs[lr][lc+5]=b1.y; Bs[lr][lc+6]=b1.z; Bs[lr][lc+7]=b1.w;
        } else {             // x / Wih region with zero-fill padding
            #pragma unroll
            for (int u = 0; u < 8; ++u) {
                const int k  = gk + u;
                const int xk = k - H_;
                float va = 0.f, vb = 0.f;
                if (xk >= 0 && xk < FEAT_) {
                    va = xbuf[(size_t)(row0 + lr) * x_stride + xk];
                    vb = Wih[(size_t)(col0 + lr) * FEAT_ + xk];
                }
                As[lr][lc+u] = va;
                Bs[lr][lc+u] = vb;
            }
        }
        __syncthreads();

        #pragma unroll
        for (int kk = 0; kk < BK; ++kk) {
            float a[4], b[4];
            #pragma unroll
            for (int i = 0; i < 4; ++i) a[i] = As[ty*4 + i][kk];
            #pragma unroll
            for (int j = 0; j < 4; ++j) b[j] = Bs[tx*4 + j][kk];
            #pragma unroll
            for (int i = 0; i < 4; ++i)
                #pragma unroll
                for (int j = 0; j < 4; ++j)
                    acc[i][j] = fmaf(a[i], b[j], acc[i][j]);
        }
        __syncthreads();
    }

    const int c0 = col0 + tx * 4;
    #pragma unroll
    for (int i = 0; i < 4; ++i) {
        const int row = row0 + ty * 4 + i;
        float4 v;
        v.x = acc[i][0] + bih[c0+0] + bhh[c0+0];
        v.y = acc[i][1] + bih[c0+1] + bhh[c0+1];
        v.z = acc[i][2] + bih[c0+2] + bhh[c0+2];
        v.w = acc[i][3] + bih[c0+3] + bhh[c0+3];
        *(float4*)(gates + (size_t)row * G4_ + c0) = v;
    }
}

// ---------------------------------------------------------------------------
// LSTM cell: i,f,g,o at gate cols j, j+H, j+2H, j+3H.
// Handles 1 or 2 (pe+ve) state sets in one launch.
// ---------------------------------------------------------------------------
__global__ __launch_bounds__(256)
void cell_kernel(const float* __restrict__ g0, float* __restrict__ h0, float* __restrict__ c0,
                 const float* __restrict__ g1, float* __restrict__ h1, float* __restrict__ c1,
                 int nsets)
{
    const int idx   = blockIdx.x * blockDim.x + threadIdx.x;
    const int total = nsets * B_ * H_;
    if (idx >= total) return;
    const float* g; float* h; float* c; int e;
    if (idx < B_ * H_) { g = g0; h = h0; c = c0; e = idx; }
    else               { g = g1; h = h1; c = c1; e = idx - B_ * H_; }
    const int b = e >> 10;
    const int j = e & 1023;
    const size_t base = (size_t)b * G4_ + j;
    const float ig = g[base];
    const float fg = g[base +     H_];
    const float gg = g[base + 2 * H_];
    const float og = g[base + 3 * H_];
    const float cc = sigmoidf_(fg) * c[e] + sigmoidf_(ig) * tanhf(gg);
    const float hh = sigmoidf_(og) * tanhf(cc);
    c[e] = cc;
    h[e] = hh;
}

// h_dec = h_pe + h_ve ; c_dec = c_pe + c_ve
__global__ __launch_bounds__(256)
void combine_kernel(const float* __restrict__ hp, const float* __restrict__ hv,
                    const float* __restrict__ cp, const float* __restrict__ cv,
                    float* __restrict__ hd, float* __restrict__ cd)
{
    const int idx = blockIdx.x * blockDim.x + threadIdx.x;
    if (idx >= B_ * H_) return;
    hd[idx] = hp[idx] + hv[idx];
    cd[idx] = cp[idx] + cv[idx];
}

// ---------------------------------------------------------------------------
// Decoder output projection, fused with clip, comp_vel write, and running
// cumsum for comp_pose. One block per batch row; h row staged in LDS.
// ---------------------------------------------------------------------------
__global__ __launch_bounds__(128)
void fc_kernel(const float* __restrict__ h,
               const float* __restrict__ fcW,   // FEAT x H, K-contiguous
               const float* __restrict__ fcb,
               float* __restrict__ acc_pose,    // B x FEAT running pose
               float* __restrict__ out_fb,      // B x FEAT next decoder input
               float* __restrict__ out, int t)
{
    __shared__ float hs[H_];
    const int b = blockIdx.x;
    for (int k = threadIdx.x; k < H_; k += 128) hs[k] = h[(size_t)b * H_ + k];
    __syncthreads();
    const int f = threadIdx.x;
    if (f < FEAT_) {
        const float* w = fcW + (size_t)f * H_;
        float s = fcb[f];
        #pragma unroll 4
        for (int k = 0; k < H_; ++k) s = fmaf(hs[k], w[k], s);
        s = fminf(fmaxf(s, -1.0f), 1.0f);
        const float p = acc_pose[b * FEAT_ + f] + s;
        acc_pose[b * FEAT_ + f] = p;
        out_fb[b * FEAT_ + f]   = s;
        out[OFF_CV + ((size_t)b * 49 + t) * FEAT_ + f]     = s;
        out[OFF_CP + ((size_t)b * 50 + t + 1) * FEAT_ + f] = p;
    }
}

// ---------------------------------------------------------------------------
// Prep: vel (with noise mask), out0 = vel[:, 48, :], future_pose passthrough,
// comp_pose[:,0,:] = pose[:,0,:], acc_pose init.
// ---------------------------------------------------------------------------
__global__ __launch_bounds__(256)
void prep_kernel(const float* __restrict__ pose,
                 const float* __restrict__ fut,
                 const int* __restrict__ noise,
                 float* __restrict__ vel,
                 float* __restrict__ out_fb,
                 float* __restrict__ acc_pose,
                 float* __restrict__ out)
{
    const size_t NV = (size_t)B_ * 49 * FEAT_;  // 3,763,200
    const size_t NF = (size_t)B_ * 25 * FEAT_;  // 1,920,000
    const size_t NP = (size_t)B_ * FEAT_;       //    76,800
    const size_t total = NV + NF + NP;
    for (size_t idx = (size_t)blockIdx.x * blockDim.x + threadIdx.x;
         idx < total; idx += (size_t)gridDim.x * blockDim.x) {
        if (idx < NV) {
            const size_t f   = idx % FEAT_;
            const size_t rem = idx / FEAT_;
            const size_t t   = rem % 49;
            const size_t b   = rem / 49;
            float v = pose[(b * 50 + t + 1) * FEAT_ + f]
                    - pose[(b * 50 + t) * FEAT_ + f];
            if (noise[(b * 50 + t + 1) * 25 + f / 3] == 1) v = 0.f;
            vel[idx] = v;
            if (t == 48) out_fb[b * FEAT_ + f] = v;
        } else if (idx < NV + NF) {
            const size_t i = idx - NV;
            out[i] = fut[i];
        } else {
            const size_t i = idx - NV - NF;
            const size_t b = i / FEAT_, f = i % FEAT_;
            const float p0 = pose[b * 50 * FEAT_ + f];
            acc_pose[i] = p0;
            out[OFF_CP + b * 50 * FEAT_ + f] = p0;
        }
    }
}

extern "C" void kernel_launch(void* const* d_in, const int* in_sizes, int n_in,
                              void* d_out, int out_size, void* d_ws, size_t ws_size,
                              hipStream_t stream) {
    const float* pose    = (const float*)d_in[0];
    const float* fut     = (const float*)d_in[1];
    const int*   noise   = (const int*)  d_in[2];
    const float* pe_Wih  = (const float*)d_in[3];
    const float* pe_Whh  = (const float*)d_in[4];
    const float* pe_bih  = (const float*)d_in[5];
    const float* pe_bhh  = (const float*)d_in[6];
    const float* ve_Wih  = (const float*)d_in[7];
    const float* ve_Whh  = (const float*)d_in[8];
    const float* ve_bih  = (const float*)d_in[9];
    const float* ve_bhh  = (const float*)d_in[10];
    const float* de_Wih  = (const float*)d_in[11];
    const float* de_Whh  = (const float*)d_in[12];
    const float* de_bih  = (const float*)d_in[13];
    const float* de_bhh  = (const float*)d_in[14];
    const float* fc_W    = (const float*)d_in[15];
    const float* fc_b    = (const float*)d_in[16];
    float* out = (float*)d_out;
    float* ws  = (float*)d_ws;

    // workspace layout (floats), total ~18.6M floats = 74.4 MB
    float* vel    = ws;                    // 3,763,200
    float* h_pe   = vel   + 3763200;       // 1,048,576 each; h_pe..c_ve contiguous
    float* c_pe   = h_pe  + 1048576;
    float* h_ve   = c_pe  + 1048576;
    float* c_ve   = h_ve  + 1048576;
    float* h_de   = c_ve  + 1048576;
    float* c_de   = h_de  + 1048576;
    float* g_pe   = c_de  + 1048576;       // 4,194,304
    float* g_ve   = g_pe  + 4194304;       // 4,194,304
    float* out_fb = g_ve  + 4194304;       // 76,800
    float* accp   = out_fb + 76800;        // 76,800

    // zero h0/c0 for both encoders (contiguous 16 MB)
    hipMemsetAsync(h_pe, 0, (size_t)4 * 1048576 * sizeof(float), stream);

    prep_kernel<<<4096, 256, 0, stream>>>(pose, fut, noise, vel, out_fb, accp, out);

    const dim3 ggrid(G4_ / BN, B_ / BM);   // (64, 16) = 1024 blocks

    // --- encoders: pe runs 50 steps, ve runs 49 (concurrent on the stream) ---
    for (int t = 0; t < 50; ++t) {
        gates_gemm_kernel<<<ggrid, 256, 0, stream>>>(
            h_pe, pose + (size_t)t * FEAT_, 50 * FEAT_,
            pe_Whh, pe_Wih, pe_bih, pe_bhh, g_pe);
        if (t < 49)
            gates_gemm_kernel<<<ggrid, 256, 0, stream>>>(
                h_ve, vel + (size_t)t * FEAT_, 49 * FEAT_,
                ve_Whh, ve_Wih, ve_bih, ve_bhh, g_ve);
        const int nsets = (t < 49) ? 2 : 1;
        cell_kernel<<<(nsets * B_ * H_ + 255) / 256, 256, 0, stream>>>(
            g_pe, h_pe, c_pe, g_ve, h_ve, c_ve, nsets);
    }

    combine_kernel<<<(B_ * H_ + 255) / 256, 256, 0, stream>>>(
        h_pe, h_ve, c_pe, c_ve, h_de, c_de);

    // --- decoder: 49 steps, feedback through out_fb ---
    for (int t = 0; t < 49; ++t) {
        gates_gemm_kernel<<<ggrid, 256, 0, stream>>>(
            h_de, out_fb, FEAT_,
            de_Whh, de_Wih, de_bih, de_bhh, g_pe);
        cell_kernel<<<(B_ * H_ + 255) / 256, 256, 0, stream>>>(
            g_pe, h_de, c_de, nullptr, nullptr, nullptr, 1);
        fc_kernel<<<B_, 128, 0, stream>>>(h_de, fc_W, fc_b, accp, out_fb, out, t);
    }
}

// Round 2
// 4796.813 us; speedup vs baseline: 6.4683x; 6.4683x over previous
//
#include <hip/hip_runtime.h>

typedef unsigned short ushort_t;
typedef __attribute__((ext_vector_type(8))) short bf16x8;
typedef __attribute__((ext_vector_type(4))) float f32x4;

#define B_    1024
#define H_    1024
#define FEAT_ 75
#define KP_   1120          // packed K: 1024 h + 75 x + 21 zero pad
#define NK_   35            // K-steps of 32
#define OFF_CP 1920000UL    // 1024*25*75
#define OFF_CV 5760000UL    // OFF_CP + 1024*50*75

__device__ __forceinline__ float bf2f(ushort_t u) {
    unsigned x = ((unsigned)u) << 16;
    float f; __builtin_memcpy(&f, &x, 4); return f;
}
__device__ __forceinline__ ushort_t f2bf(float f) {
    unsigned x; __builtin_memcpy(&x, &f, 4);
    x += 0x7fffu + ((x >> 16) & 1u);          // RNE
    return (ushort_t)(x >> 16);
}
__device__ __forceinline__ float sigm(float x) { return 1.f / (1.f + __expf(-x)); }

__device__ __forceinline__ void gload16(const void* g, void* l) {
    __builtin_amdgcn_global_load_lds(
        (const __attribute__((address_space(1))) void*)g,
        (__attribute__((address_space(3))) void*)l, 16, 0, 0);
}

// ---------------------------------------------------------------------------
// Fused LSTM step: gates GEMM (bf16 MFMA, K=1120 packed) + cell + h/x write.
// Block: 64 batch rows x 64 j-cols (x4 gate panels). Wave w: all 64 rows x
// j-sub [w*16, w*16+16) x 4 gates -> 4 M-tiles x 4 N-tiles of 16x16x32 MFMA.
// A ping-pong: reads Ain (h_{t-1} | x_t), epilogue writes h_t into Aout;
// ct==0 blocks also copy x_{t+1} into Aout (encoders).
// ---------------------------------------------------------------------------
struct StepArgs {
    const ushort_t* Ain[2];
    ushort_t*       Aout[2];
    const ushort_t* W[2];       // packed 4096 x 1120 bf16
    const float*    bias[2];    // 4096 combined bih+bhh
    float*          c[2];       // B x H fp32 cell state (in-place)
    const ushort_t* xnext[2];   // x_{t+1} source (row stride xstride), or null
    int             xstride[2];
};

__global__ __launch_bounds__(256)
void lstm_step_kernel(StepArgs sa)
{
    __shared__ __align__(16) char lds[2 * 20480];   // per buf: A 4KB + B 16KB

    const int p = blockIdx.z;
    const ushort_t* __restrict__ Ain  = sa.Ain[p];
    ushort_t*       __restrict__ Aout = sa.Aout[p];
    const ushort_t* __restrict__ Wt   = sa.W[p];
    const float*    __restrict__ bias = sa.bias[p];
    float*          __restrict__ cst  = sa.c[p];
    const ushort_t* xnext = sa.xnext[p];
    const int xstride = sa.xstride[p];

    const int tid  = threadIdx.x;
    const int w    = tid >> 6;       // wave 0..3
    const int l    = tid & 63;       // lane
    const int ct   = blockIdx.x;     // j-tile 0..15
    const int rt   = blockIdx.y;     // row-tile 0..15
    const int j0   = ct * 64;
    const int row0 = rt * 64;

    // ---- x_{t+1} copy into Aout (encoders only, ct==0 blocks) ----
    if (ct == 0 && xnext) {
        for (int idx = tid; idx < 64 * 96; idx += 256) {
            const int r  = idx / 96;
            const int xi = idx - r * 96;
            const int grow = row0 + r;
            ushort_t v = (xi < FEAT_) ? xnext[(size_t)grow * xstride + xi] : (ushort_t)0;
            Aout[(size_t)grow * KP_ + 1024 + xi] = v;
        }
    }

    // ---- staging addresses (global_load_lds: per-lane global src, uniform LDS base) ----
    const int lc4  = l & 3;                 // 16B chunk slot within 64B row
    const int lr4  = l >> 2;                // row within 16-row issue
    const int csrc = lc4 ^ (lr4 & 3);       // inverse-swizzled source chunk (G21)

    const ushort_t* agsrc = Ain + (size_t)(row0 + w * 16 + lr4) * KP_ + csrc * 8;
    char* aldst = lds + (w * 16) * 64;

    const ushort_t* bgsrc[4];
    char* bldst[4];
    #pragma unroll
    for (int i = 0; i < 4; ++i) {
        const int wcol = w * 1024 + j0 + i * 16 + lr4;   // gate panel w
        bgsrc[i] = Wt + (size_t)wcol * KP_ + csrc * 8;
        bldst[i] = lds + 4096 + (w * 64 + i * 16) * 64;
    }

    // ---- read offsets: LDS[r][c] holds global chunk c ^ (r&3) ----
    const int chsw = (((l >> 4) ^ (l & 3)) << 4);
    int aoff[4], boff[4];
    #pragma unroll
    for (int m = 0; m < 4; ++m) aoff[m] = (m * 16 + (l & 15)) * 64 + chsw;
    #pragma unroll
    for (int g = 0; g < 4; ++g) boff[g] = 4096 + (g * 64 + w * 16 + (l & 15)) * 64 + chsw;

    f32x4 acc[4][4];
    #pragma unroll
    for (int m = 0; m < 4; ++m)
        #pragma unroll
        for (int g = 0; g < 4; ++g)
            acc[m][g] = (f32x4){0.f, 0.f, 0.f, 0.f};

    // ---- K loop: stage(kt+1) || ds_read+MFMA(kt); one barrier per step ----
    {
        const size_t k0 = 0;
        gload16(agsrc + k0, aldst);
        #pragma unroll
        for (int i = 0; i < 4; ++i) gload16(bgsrc[i] + k0, bldst[i]);
    }
    __syncthreads();

    int bi = 0;
    for (int kt = 0; kt < NK_; ++kt) {
        if (kt + 1 < NK_) {
            const size_t k0 = (size_t)(kt + 1) * 32;
            const int nb = (bi ^ 1) * 20480;
            gload16(agsrc + k0, aldst + nb);
            #pragma unroll
            for (int i = 0; i < 4; ++i) gload16(bgsrc[i] + k0, bldst[i] + nb);
        }
        const char* bp = lds + bi * 20480;
        bf16x8 a[4], b[4];
        #pragma unroll
        for (int m = 0; m < 4; ++m) a[m] = *(const bf16x8*)(bp + aoff[m]);
        #pragma unroll
        for (int g = 0; g < 4; ++g) b[g] = *(const bf16x8*)(bp + boff[g]);
        #pragma unroll
        for (int m = 0; m < 4; ++m)
            #pragma unroll
            for (int g = 0; g < 4; ++g)
                acc[m][g] = __builtin_amdgcn_mfma_f32_16x16x32_bf16(a[m], b[g], acc[m][g], 0, 0, 0);
        __syncthreads();   // drains vmcnt (stage done) + lgkm (reads done)
        bi ^= 1;
    }

    // ---- epilogue: all 4 gates for (row, j) live in this lane's acc[m][*][r] ----
    const int jw = j0 + w * 16 + (l & 15);
    #pragma unroll
    for (int m = 0; m < 4; ++m) {
        #pragma unroll
        for (int r = 0; r < 4; ++r) {
            const int grow = row0 + m * 16 + ((l >> 4) << 2) + r;
            const float gi = acc[m][0][r] + bias[jw];
            const float gf = acc[m][1][r] + bias[1024 + jw];
            const float gg = acc[m][2][r] + bias[2048 + jw];
            const float go = acc[m][3][r] + bias[3072 + jw];
            const size_t ce = (size_t)grow * H_ + jw;
            const float cn = sigm(gf) * cst[ce] + sigm(gi) * tanhf(gg);
            cst[ce] = cn;
            Aout[(size_t)grow * KP_ + jw] = f2bf(sigm(go) * tanhf(cn));
        }
    }
}

// ---------------------------------------------------------------------------
// Pack: 3 weight sets -> bf16 [4096][1120] (Whh | Wih | 0pad), combined
// biases, fc_W -> bf16.
// ---------------------------------------------------------------------------
__global__ __launch_bounds__(256)
void pack_kernel(const float* __restrict__ peWih, const float* __restrict__ peWhh,
                 const float* __restrict__ veWih, const float* __restrict__ veWhh,
                 const float* __restrict__ deWih, const float* __restrict__ deWhh,
                 const float* __restrict__ pe_bih, const float* __restrict__ pe_bhh,
                 const float* __restrict__ ve_bih, const float* __restrict__ ve_bhh,
                 const float* __restrict__ de_bih, const float* __restrict__ de_bhh,
                 const float* __restrict__ fcW,
                 ushort_t* __restrict__ Wp, float* __restrict__ biasp,
                 ushort_t* __restrict__ fcWb)
{
    const size_t PER = 4096UL * KP_;
    const size_t NW  = 3UL * PER;
    const size_t NB  = 3UL * 4096;
    const size_t NF  = 75UL * 1024;
    for (size_t idx = (size_t)blockIdx.x * blockDim.x + threadIdx.x;
         idx < NW + NB + NF; idx += (size_t)gridDim.x * blockDim.x) {
        if (idx < NW) {
            const int p   = (int)(idx / PER);
            const size_t rem = idx % PER;
            const int row = (int)(rem / KP_);
            const int k   = (int)(rem % KP_);
            const float* Whh = (p == 0) ? peWhh : (p == 1) ? veWhh : deWhh;
            const float* Wih = (p == 0) ? peWih : (p == 1) ? veWih : deWih;
            float v = 0.f;
            if (k < 1024)      v = Whh[(size_t)row * 1024 + k];
            else if (k < 1099) v = Wih[(size_t)row * 75 + (k - 1024)];
            Wp[idx] = f2bf(v);
        } else if (idx < NW + NB) {
            const size_t i = idx - NW;
            const int p = (int)(i / 4096);
            const int r = (int)(i % 4096);
            const float* bih = (p == 0) ? pe_bih : (p == 1) ? ve_bih : de_bih;
            const float* bhh = (p == 0) ? pe_bhh : (p == 1) ? ve_bhh : de_bhh;
            biasp[i] = bih[r] + bhh[r];
        } else {
            const size_t i = idx - NW - NB;
            fcWb[i] = f2bf(fcW[i]);
        }
    }
}

// ---------------------------------------------------------------------------
// Prep: pose->bf16, vel (noise-masked)->bf16, x inits for A_pe0/A_ve0/A_dec0,
// future passthrough, comp_pose[:,0], acc_pose init.
// ---------------------------------------------------------------------------
__global__ __launch_bounds__(256)
void prep_kernel(const float* __restrict__ pose, const float* __restrict__ fut,
                 const int* __restrict__ noise,
                 ushort_t* __restrict__ pose_bf, ushort_t* __restrict__ vel_bf,
                 ushort_t* __restrict__ A_pe0, ushort_t* __restrict__ A_ve0,
                 ushort_t* __restrict__ A_dec0,
                 float* __restrict__ accp, float* __restrict__ out)
{
    const size_t N0 = 1024UL * 50 * 75;
    const size_t N1 = 1024UL * 49 * 75;
    const size_t N2 = 1920000UL;
    const size_t N3 = 76800UL;
    for (size_t idx = (size_t)blockIdx.x * blockDim.x + threadIdx.x;
         idx < N0 + N1 + N2 + N3; idx += (size_t)gridDim.x * blockDim.x) {
        if (idx < N0) {
            pose_bf[idx] = f2bf(pose[idx]);
        } else if (idx < N0 + N1) {
            const size_t i = idx - N0;
            const int f = (int)(i % 75);
            const size_t rem = i / 75;
            const int t = (int)(rem % 49);
            const size_t b = rem / 49;
            float v = pose[(b * 50 + t + 1) * 75 + f] - pose[(b * 50 + t) * 75 + f];
            if (noise[(b * 50 + t + 1) * 25 + f / 3] == 1) v = 0.f;
            const ushort_t vb = f2bf(v);
            vel_bf[i] = vb;
            if (t == 0)  A_ve0[b * KP_ + 1024 + f]  = vb;
            if (t == 48) A_dec0[b * KP_ + 1024 + f] = vb;
        } else if (idx < N0 + N1 + N2) {
            const size_t i = idx - N0 - N1;
            out[i] = fut[i];
        } else {
            const size_t i = idx - N0 - N1 - N2;
            const size_t b = i / 75;
            const int f = (int)(i % 75);
            const float p0 = pose[b * 50 * 75 + f];
            A_pe0[b * KP_ + 1024 + f] = f2bf(p0);
            accp[i] = p0;
            out[OFF_CP + b * 50 * 75 + f] = p0;
        }
    }
}

// h_dec0 = bf16(h_pe + h_ve) into A_dec0; c_de = c_pe + c_ve
__global__ __launch_bounds__(256)
void combine_kernel(const ushort_t* __restrict__ hpe, const ushort_t* __restrict__ hve,
                    const float* __restrict__ cpe, const float* __restrict__ cve,
                    ushort_t* __restrict__ Adec0, float* __restrict__ cde)
{
    const int idx = blockIdx.x * blockDim.x + threadIdx.x;
    if (idx >= B_ * H_) return;
    const int b = idx >> 10, j = idx & 1023;
    Adec0[(size_t)b * KP_ + j] = f2bf(bf2f(hpe[(size_t)b * KP_ + j]) + bf2f(hve[(size_t)b * KP_ + j]));
    cde[idx] = cpe[idx] + cve[idx];
}

// ---------------------------------------------------------------------------
// Decoder fc: s = clip(h @ fcW^T + b), fused comp_vel/comp_pose writes,
// cumsum, and bf16 feedback into A_dec x-region.
// ---------------------------------------------------------------------------
__global__ __launch_bounds__(128)
void fc_kernel(const ushort_t* __restrict__ Adec,   // buffer holding h_t (and x dest)
               ushort_t* __restrict__ Adec_w,
               const ushort_t* __restrict__ fcWb, const float* __restrict__ fcb,
               float* __restrict__ accp, float* __restrict__ out, int t)
{
    __shared__ float hs[1024];
    const int b = blockIdx.x;
    const ushort_t* hrow = Adec + (size_t)b * KP_;
    {
        const int k = threadIdx.x * 8;
        const bf16x8 v = *(const bf16x8*)(hrow + k);
        #pragma unroll
        for (int u = 0; u < 8; ++u) hs[k + u] = bf2f((ushort_t)v[u]);
    }
    __syncthreads();
    const int f = threadIdx.x;
    if (f < FEAT_) {
        const ushort_t* wr = fcWb + (size_t)f * 1024;
        float s = fcb[f];
        for (int k = 0; k < 1024; k += 8) {
            const bf16x8 wv = *(const bf16x8*)(wr + k);
            #pragma unroll
            for (int u = 0; u < 8; ++u) s = fmaf(hs[k + u], bf2f((ushort_t)wv[u]), s);
        }
        s = fminf(fmaxf(s, -1.f), 1.f);
        const float p = accp[b * FEAT_ + f] + s;
        accp[b * FEAT_ + f] = p;
        out[OFF_CV + ((size_t)b * 49 + t) * FEAT_ + f]     = s;
        out[OFF_CP + ((size_t)b * 50 + t + 1) * FEAT_ + f] = p;
        Adec_w[(size_t)b * KP_ + 1024 + f] = f2bf(s);
    }
}

extern "C" void kernel_launch(void* const* d_in, const int* in_sizes, int n_in,
                              void* d_out, int out_size, void* d_ws, size_t ws_size,
                              hipStream_t stream) {
    const float* pose   = (const float*)d_in[0];
    const float* fut    = (const float*)d_in[1];
    const int*   noise  = (const int*)  d_in[2];
    const float* peWih  = (const float*)d_in[3];
    const float* peWhh  = (const float*)d_in[4];
    const float* pe_bih = (const float*)d_in[5];
    const float* pe_bhh = (const float*)d_in[6];
    const float* veWih  = (const float*)d_in[7];
    const float* veWhh  = (const float*)d_in[8];
    const float* ve_bih = (const float*)d_in[9];
    const float* ve_bhh = (const float*)d_in[10];
    const float* deWih  = (const float*)d_in[11];
    const float* deWhh  = (const float*)d_in[12];
    const float* de_bih = (const float*)d_in[13];
    const float* de_bhh = (const float*)d_in[14];
    const float* fcW    = (const float*)d_in[15];
    const float* fcb    = (const float*)d_in[16];
    float* out = (float*)d_out;

    char* base = (char*)d_ws;
    // A buffers: 6 x 1024x1120 bf16 (pe0,pe1,ve0,ve1,dec0,dec1)
    ushort_t* Ape[2]  = {(ushort_t*)(base + 0UL * 2293760), (ushort_t*)(base + 1UL * 2293760)};
    ushort_t* Ave[2]  = {(ushort_t*)(base + 2UL * 2293760), (ushort_t*)(base + 3UL * 2293760)};
    ushort_t* Adec[2] = {(ushort_t*)(base + 4UL * 2293760), (ushort_t*)(base + 5UL * 2293760)};
    float* c_pe = (float*)(base + 13762560);
    float* c_ve = c_pe + 1048576;
    float* c_de = c_ve + 1048576;
    ushort_t* Wp    = (ushort_t*)(base + 26345472);   // 3 x 4096 x 1120
    float*    biasp = (float*)   (base + 53870592);   // 3 x 4096
    ushort_t* fcWb  = (ushort_t*)(base + 53919744);   // 75 x 1024
    ushort_t* pose_bf = (ushort_t*)(base + 54073344); // 1024x50x75
    ushort_t* vel_bf  = (ushort_t*)(base + 61753344); // 1024x49x75
    float*    accp    = (float*)   (base + 69279744); // 1024x75

    // zero: all 6 A buffers + c_pe + c_ve (contiguous)
    hipMemsetAsync(base, 0, 22151168, stream);

    pack_kernel<<<2048, 256, 0, stream>>>(peWih, peWhh, veWih, veWhh, deWih, deWhh,
                                          pe_bih, pe_bhh, ve_bih, ve_bhh, de_bih, de_bhh,
                                          fcW, Wp, biasp, fcWb);
    prep_kernel<<<2048, 256, 0, stream>>>(pose, fut, noise, pose_bf, vel_bf,
                                          Ape[0], Ave[0], Adec[0], accp, out);

    const ushort_t* Wpe = Wp;
    const ushort_t* Wve = Wp + 4587520;
    const ushort_t* Wde = Wp + 9175040;

    // --- encoders: dual launch (pe + ve) for t<49, single pe at t=49 ---
    for (int t = 0; t < 49; ++t) {
        StepArgs sa;
        sa.Ain[0] = Ape[t & 1];  sa.Aout[0] = Ape[(t + 1) & 1];
        sa.W[0] = Wpe; sa.bias[0] = biasp; sa.c[0] = c_pe;
        sa.xnext[0] = pose_bf + (size_t)(t + 1) * 75; sa.xstride[0] = 3750;
        sa.Ain[1] = Ave[t & 1];  sa.Aout[1] = Ave[(t + 1) & 1];
        sa.W[1] = Wve; sa.bias[1] = biasp + 4096; sa.c[1] = c_ve;
        sa.xnext[1] = (t < 48) ? (vel_bf + (size_t)(t + 1) * 75) : nullptr;
        sa.xstride[1] = 3675;
        lstm_step_kernel<<<dim3(16, 16, 2), 256, 0, stream>>>(sa);
    }
    {
        StepArgs sa;
        sa.Ain[0] = Ape[1]; sa.Aout[0] = Ape[0];
        sa.W[0] = Wpe; sa.bias[0] = biasp; sa.c[0] = c_pe;
        sa.xnext[0] = nullptr; sa.xstride[0] = 3750;
        sa.Ain[1] = sa.Ain[0]; sa.Aout[1] = sa.Aout[0];
        sa.W[1] = sa.W[0]; sa.bias[1] = sa.bias[0]; sa.c[1] = sa.c[0];
        sa.xnext[1] = nullptr; sa.xstride[1] = 3750;
        lstm_step_kernel<<<dim3(16, 16, 1), 256, 0, stream>>>(sa);
    }

    combine_kernel<<<4096, 256, 0, stream>>>(Ape[0], Ave[1], c_pe, c_ve, Adec[0], c_de);

    // --- decoder: 49 steps, fc feeds back into the next A_dec buffer ---
    for (int d = 0; d < 49; ++d) {
        StepArgs sa;
        sa.Ain[0] = Adec[d & 1]; sa.Aout[0] = Adec[(d + 1) & 1];
        sa.W[0] = Wde; sa.bias[0] = biasp + 8192; sa.c[0] = c_de;
        sa.xnext[0] = nullptr; sa.xstride[0] = 0;
        sa.Ain[1] = sa.Ain[0]; sa.Aout[1] = sa.Aout[0];
        sa.W[1] = sa.W[0]; sa.bias[1] = sa.bias[0]; sa.c[1] = sa.c[0];
        sa.xnext[1] = nullptr; sa.xstride[1] = 0;
        lstm_step_kernel<<<dim3(16, 16, 1), 256, 0, stream>>>(sa);
        fc_kernel<<<B_, 128, 0, stream>>>(Adec[(d + 1) & 1], Adec[(d + 1) & 1],
                                          fcWb, fcb, accp, out, d);
    }
}

// Round 3
// 4060.842 us; speedup vs baseline: 7.6406x; 1.1812x over previous
//
#include <hip/hip_runtime.h>

typedef unsigned short ushort_t;
typedef __attribute__((ext_vector_type(8))) short bf16x8;
typedef __attribute__((ext_vector_type(4))) float f32x4;

#define B_    1024
#define H_    1024
#define FEAT_ 75
#define KP_   1120          // packed K: 1024 h + 75 x + 21 zero pad
#define NK_   35            // K-steps of 32
#define OFF_CP 1920000UL    // 1024*25*75
#define OFF_CV 5760000UL    // OFF_CP + 1024*50*75

__device__ __forceinline__ float bf2f(ushort_t u) {
    unsigned x = ((unsigned)u) << 16;
    float f; __builtin_memcpy(&f, &x, 4); return f;
}
__device__ __forceinline__ ushort_t f2bf(float f) {
    unsigned x; __builtin_memcpy(&x, &f, 4);
    x += 0x7fffu + ((x >> 16) & 1u);          // RNE
    return (ushort_t)(x >> 16);
}
__device__ __forceinline__ float sigm(float x) { return 1.f / (1.f + __expf(-x)); }

__device__ __forceinline__ void gload16(const void* g, void* l) {
    __builtin_amdgcn_global_load_lds(
        (const __attribute__((address_space(1))) void*)g,
        (__attribute__((address_space(3))) void*)l, 16, 0, 0);
}

// ---------------------------------------------------------------------------
// Fused LSTM step: gates GEMM (bf16 MFMA, K=1120 packed) + cell + h/x write.
// Block: 64 batch rows x 64 j-cols (x4 gate panels), 4 waves.
// Grid is 1D + XCD-swizzled (T1): flat%8 = XCD; each XCD owns whole col-tiles
// (all 16 row-tiles) so its ~2.3 MB weight slice stays L2-resident across
// row-tiles AND across timestep dispatches.
// K-loop is the T3/T4 minimum 2-phase: issue stage(kt+1), counted
// s_waitcnt vmcnt(5), raw s_barrier, ds_read+MFMA, s_barrier. Never vmcnt(0)
// in the main loop -> stage latency hides under the previous step's compute.
// ---------------------------------------------------------------------------
struct StepArgs {
    const ushort_t* Ain[2];
    ushort_t*       Aout[2];
    const ushort_t* W[2];       // packed 4096 x 1120 bf16
    const float*    bias[2];    // 4096 combined bih+bhh
    float*          c[2];       // B x H fp32 cell state (in-place)
    const ushort_t* xnext[2];   // x_{t+1} source (row stride xstride), or null
    int             xstride[2];
};

__global__ __launch_bounds__(256)
void lstm_step_kernel(StepArgs sa)
{
    __shared__ __align__(16) char lds[2 * 20480];   // per buf: A 4KB + B 16KB

    // ---- XCD-aware decode: flat -> (p, ct, rt) ----
    const int flat = blockIdx.x;
    const int xcd  = flat & 7;
    const int slot = flat >> 3;
    int p, ct, rt;
    if (gridDim.x == 512) {            // dual problem (pe+ve encoders)
        const int cg = (xcd << 2) + (slot >> 4);   // 0..31
        p  = cg >> 4;
        ct = cg & 15;
    } else {                           // single problem
        const int cg = (xcd << 1) + (slot >> 4);   // 0..15
        p  = 0;
        ct = cg;
    }
    rt = slot & 15;

    const ushort_t* __restrict__ Ain  = sa.Ain[p];
    ushort_t*       __restrict__ Aout = sa.Aout[p];
    const ushort_t* __restrict__ Wt   = sa.W[p];
    const float*    __restrict__ bias = sa.bias[p];
    float*          __restrict__ cst  = sa.c[p];
    const ushort_t* xnext = sa.xnext[p];
    const int xstride = sa.xstride[p];

    const int tid  = threadIdx.x;
    const int w    = tid >> 6;       // wave 0..3
    const int l    = tid & 63;       // lane
    const int j0   = ct * 64;
    const int row0 = rt * 64;

    // ---- x_{t+1} copy into Aout (encoders only, ct==0 blocks) ----
    if (ct == 0 && xnext) {
        for (int idx = tid; idx < 64 * 96; idx += 256) {
            const int r  = idx / 96;
            const int xi = idx - r * 96;
            const int grow = row0 + r;
            ushort_t v = (xi < FEAT_) ? xnext[(size_t)grow * xstride + xi] : (ushort_t)0;
            Aout[(size_t)grow * KP_ + 1024 + xi] = v;
        }
    }

    // ---- staging addresses (global_load_lds: per-lane global src, uniform LDS base) ----
    const int lc4  = l & 3;                 // 16B chunk slot within 64B row
    const int lr4  = l >> 2;                // row within 16-row issue
    const int csrc = lc4 ^ (lr4 & 3);       // inverse-swizzled source chunk (G21)

    const ushort_t* agsrc = Ain + (size_t)(row0 + w * 16 + lr4) * KP_ + csrc * 8;
    char* aldst = lds + (w * 16) * 64;

    const ushort_t* bgsrc[4];
    char* bldst[4];
    #pragma unroll
    for (int i = 0; i < 4; ++i) {
        const int wcol = w * 1024 + j0 + i * 16 + lr4;   // gate panel w
        bgsrc[i] = Wt + (size_t)wcol * KP_ + csrc * 8;
        bldst[i] = lds + 4096 + (w * 64 + i * 16) * 64;
    }

    // ---- read offsets: LDS[r][c] holds global chunk c ^ (r&3) ----
    const int chsw = (((l >> 4) ^ (l & 3)) << 4);
    int aoff[4], boff[4];
    #pragma unroll
    for (int m = 0; m < 4; ++m) aoff[m] = (m * 16 + (l & 15)) * 64 + chsw;
    #pragma unroll
    for (int g = 0; g < 4; ++g) boff[g] = 4096 + (g * 64 + w * 16 + (l & 15)) * 64 + chsw;

    f32x4 acc[4][4];
    #pragma unroll
    for (int m = 0; m < 4; ++m)
        #pragma unroll
        for (int g = 0; g < 4; ++g)
            acc[m][g] = (f32x4){0.f, 0.f, 0.f, 0.f};

    // ---- prologue: stage K-step 0 into buf0 ----
    gload16(agsrc, aldst);
    #pragma unroll
    for (int i = 0; i < 4; ++i) gload16(bgsrc[i], bldst[i]);

    // ---- main loop: 2-phase, counted vmcnt, raw barriers ----
    int bi = 0;
    for (int kt = 0; kt < NK_; ++kt) {
        if (kt + 1 < NK_) {
            const size_t k0 = (size_t)(kt + 1) * 32;
            const int nb = (bi ^ 1) * 20480;
            gload16(agsrc + k0, aldst + nb);
            #pragma unroll
            for (int i = 0; i < 4; ++i) gload16(bgsrc[i] + k0, bldst[i] + nb);
            asm volatile("s_waitcnt vmcnt(5)" ::: "memory");  // stage(kt) done; stage(kt+1) in flight
        } else {
            asm volatile("s_waitcnt vmcnt(0)" ::: "memory");  // last tile: drain
        }
        __builtin_amdgcn_s_barrier();        // all waves' stage(kt) visible
        asm volatile("" ::: "memory");

        const char* bp = lds + bi * 20480;
        bf16x8 a[4], b[4];
        #pragma unroll
        for (int m = 0; m < 4; ++m) a[m] = *(const bf16x8*)(bp + aoff[m]);
        #pragma unroll
        for (int g = 0; g < 4; ++g) b[g] = *(const bf16x8*)(bp + boff[g]);
        __builtin_amdgcn_s_setprio(1);
        #pragma unroll
        for (int m = 0; m < 4; ++m)
            #pragma unroll
            for (int g = 0; g < 4; ++g)
                acc[m][g] = __builtin_amdgcn_mfma_f32_16x16x32_bf16(a[m], b[g], acc[m][g], 0, 0, 0);
        __builtin_amdgcn_s_setprio(0);

        asm volatile("" ::: "memory");
        __builtin_amdgcn_s_barrier();        // all waves done reading buf[bi]
        bi ^= 1;
    }

    // ---- epilogue: all 4 gates for (row, j) live in this lane's acc[m][*][r] ----
    const int jw = j0 + w * 16 + (l & 15);
    const float b_i = bias[jw];
    const float b_f = bias[1024 + jw];
    const float b_g = bias[2048 + jw];
    const float b_o = bias[3072 + jw];
    #pragma unroll
    for (int m = 0; m < 4; ++m) {
        #pragma unroll
        for (int r = 0; r < 4; ++r) {
            const int grow = row0 + m * 16 + ((l >> 4) << 2) + r;
            const float gi = acc[m][0][r] + b_i;
            const float gf = acc[m][1][r] + b_f;
            const float gg = acc[m][2][r] + b_g;
            const float go = acc[m][3][r] + b_o;
            const size_t ce = (size_t)grow * H_ + jw;
            const float cn = sigm(gf) * cst[ce] + sigm(gi) * tanhf(gg);
            cst[ce] = cn;
            Aout[(size_t)grow * KP_ + jw] = f2bf(sigm(go) * tanhf(cn));
        }
    }
}

// ---------------------------------------------------------------------------
// Pack: 3 weight sets -> bf16 [4096][1120] (Whh | Wih | 0pad), combined
// biases, fc_W -> bf16.
// ---------------------------------------------------------------------------
__global__ __launch_bounds__(256)
void pack_kernel(const float* __restrict__ peWih, const float* __restrict__ peWhh,
                 const float* __restrict__ veWih, const float* __restrict__ veWhh,
                 const float* __restrict__ deWih, const float* __restrict__ deWhh,
                 const float* __restrict__ pe_bih, const float* __restrict__ pe_bhh,
                 const float* __restrict__ ve_bih, const float* __restrict__ ve_bhh,
                 const float* __restrict__ de_bih, const float* __restrict__ de_bhh,
                 const float* __restrict__ fcW,
                 ushort_t* __restrict__ Wp, float* __restrict__ biasp,
                 ushort_t* __restrict__ fcWb)
{
    const size_t PER = 4096UL * KP_;
    const size_t NW  = 3UL * PER;
    const size_t NB  = 3UL * 4096;
    const size_t NF  = 75UL * 1024;
    for (size_t idx = (size_t)blockIdx.x * blockDim.x + threadIdx.x;
         idx < NW + NB + NF; idx += (size_t)gridDim.x * blockDim.x) {
        if (idx < NW) {
            const int p   = (int)(idx / PER);
            const size_t rem = idx % PER;
            const int row = (int)(rem / KP_);
            const int k   = (int)(rem % KP_);
            const float* Whh = (p == 0) ? peWhh : (p == 1) ? veWhh : deWhh;
            const float* Wih = (p == 0) ? peWih : (p == 1) ? veWih : deWih;
            float v = 0.f;
            if (k < 1024)      v = Whh[(size_t)row * 1024 + k];
            else if (k < 1099) v = Wih[(size_t)row * 75 + (k - 1024)];
            Wp[idx] = f2bf(v);
        } else if (idx < NW + NB) {
            const size_t i = idx - NW;
            const int p = (int)(i / 4096);
            const int r = (int)(i % 4096);
            const float* bih = (p == 0) ? pe_bih : (p == 1) ? ve_bih : de_bih;
            const float* bhh = (p == 0) ? pe_bhh : (p == 1) ? ve_bhh : de_bhh;
            biasp[i] = bih[r] + bhh[r];
        } else {
            const size_t i = idx - NW - NB;
            fcWb[i] = f2bf(fcW[i]);
        }
    }
}

// ---------------------------------------------------------------------------
// Prep: pose->bf16, vel (noise-masked)->bf16, x inits for A_pe0/A_ve0/A_dec0,
// future passthrough, comp_pose[:,0], acc_pose init.
// ---------------------------------------------------------------------------
__global__ __launch_bounds__(256)
void prep_kernel(const float* __restrict__ pose, const float* __restrict__ fut,
                 const int* __restrict__ noise,
                 ushort_t* __restrict__ pose_bf, ushort_t* __restrict__ vel_bf,
                 ushort_t* __restrict__ A_pe0, ushort_t* __restrict__ A_ve0,
                 ushort_t* __restrict__ A_dec0,
                 float* __restrict__ accp, float* __restrict__ out)
{
    const size_t N0 = 1024UL * 50 * 75;
    const size_t N1 = 1024UL * 49 * 75;
    const size_t N2 = 1920000UL;
    const size_t N3 = 76800UL;
    for (size_t idx = (size_t)blockIdx.x * blockDim.x + threadIdx.x;
         idx < N0 + N1 + N2 + N3; idx += (size_t)gridDim.x * blockDim.x) {
        if (idx < N0) {
            pose_bf[idx] = f2bf(pose[idx]);
        } else if (idx < N0 + N1) {
            const size_t i = idx - N0;
            const int f = (int)(i % 75);
            const size_t rem = i / 75;
            const int t = (int)(rem % 49);
            const size_t b = rem / 49;
            float v = pose[(b * 50 + t + 1) * 75 + f] - pose[(b * 50 + t) * 75 + f];
            if (noise[(b * 50 + t + 1) * 25 + f / 3] == 1) v = 0.f;
            const ushort_t vb = f2bf(v);
            vel_bf[i] = vb;
            if (t == 0)  A_ve0[b * KP_ + 1024 + f]  = vb;
            if (t == 48) A_dec0[b * KP_ + 1024 + f] = vb;
        } else if (idx < N0 + N1 + N2) {
            const size_t i = idx - N0 - N1;
            out[i] = fut[i];
        } else {
            const size_t i = idx - N0 - N1 - N2;
            const size_t b = i / 75;
            const int f = (int)(i % 75);
            const float p0 = pose[b * 50 * 75 + f];
            A_pe0[b * KP_ + 1024 + f] = f2bf(p0);
            accp[i] = p0;
            out[OFF_CP + b * 50 * 75 + f] = p0;
        }
    }
}

// h_dec0 = bf16(h_pe + h_ve) into A_dec0; c_de = c_pe + c_ve
__global__ __launch_bounds__(256)
void combine_kernel(const ushort_t* __restrict__ hpe, const ushort_t* __restrict__ hve,
                    const float* __restrict__ cpe, const float* __restrict__ cve,
                    ushort_t* __restrict__ Adec0, float* __restrict__ cde)
{
    const int idx = blockIdx.x * blockDim.x + threadIdx.x;
    if (idx >= B_ * H_) return;
    const int b = idx >> 10, j = idx & 1023;
    Adec0[(size_t)b * KP_ + j] = f2bf(bf2f(hpe[(size_t)b * KP_ + j]) + bf2f(hve[(size_t)b * KP_ + j]));
    cde[idx] = cpe[idx] + cve[idx];
}

// ---------------------------------------------------------------------------
// Decoder fc: s = clip(h @ fcW^T + b), fused comp_vel/comp_pose writes,
// cumsum, and bf16 feedback into A_dec x-region. 4-way ILP on the dot.
// ---------------------------------------------------------------------------
__global__ __launch_bounds__(128)
void fc_kernel(const ushort_t* __restrict__ Adec,   // buffer holding h_t (and x dest)
               ushort_t* __restrict__ Adec_w,
               const ushort_t* __restrict__ fcWb, const float* __restrict__ fcb,
               float* __restrict__ accp, float* __restrict__ out, int t)
{
    __shared__ float hs[1024];
    const int b = blockIdx.x;
    const ushort_t* hrow = Adec + (size_t)b * KP_;
    {
        const int k = threadIdx.x * 8;
        const bf16x8 v = *(const bf16x8*)(hrow + k);
        #pragma unroll
        for (int u = 0; u < 8; ++u) hs[k + u] = bf2f((ushort_t)v[u]);
    }
    __syncthreads();
    const int f = threadIdx.x;
    if (f < FEAT_) {
        const ushort_t* wr = fcWb + (size_t)f * 1024;
        float s0 = fcb[f], s1 = 0.f, s2 = 0.f, s3 = 0.f;
        for (int k = 0; k < 1024; k += 32) {
            const bf16x8 w0 = *(const bf16x8*)(wr + k);
            const bf16x8 w1 = *(const bf16x8*)(wr + k + 8);
            const bf16x8 w2 = *(const bf16x8*)(wr + k + 16);
            const bf16x8 w3 = *(const bf16x8*)(wr + k + 24);
            #pragma unroll
            for (int u = 0; u < 8; ++u) {
                s0 = fmaf(hs[k + u],      bf2f((ushort_t)w0[u]), s0);
                s1 = fmaf(hs[k + 8 + u],  bf2f((ushort_t)w1[u]), s1);
                s2 = fmaf(hs[k + 16 + u], bf2f((ushort_t)w2[u]), s2);
                s3 = fmaf(hs[k + 24 + u], bf2f((ushort_t)w3[u]), s3);
            }
        }
        float s = (s0 + s1) + (s2 + s3);
        s = fminf(fmaxf(s, -1.f), 1.f);
        const float p = accp[b * FEAT_ + f] + s;
        accp[b * FEAT_ + f] = p;
        out[OFF_CV + ((size_t)b * 49 + t) * FEAT_ + f]     = s;
        out[OFF_CP + ((size_t)b * 50 + t + 1) * FEAT_ + f] = p;
        Adec_w[(size_t)b * KP_ + 1024 + f] = f2bf(s);
    }
}

extern "C" void kernel_launch(void* const* d_in, const int* in_sizes, int n_in,
                              void* d_out, int out_size, void* d_ws, size_t ws_size,
                              hipStream_t stream) {
    const float* pose   = (const float*)d_in[0];
    const float* fut    = (const float*)d_in[1];
    const int*   noise  = (const int*)  d_in[2];
    const float* peWih  = (const float*)d_in[3];
    const float* peWhh  = (const float*)d_in[4];
    const float* pe_bih = (const float*)d_in[5];
    const float* pe_bhh = (const float*)d_in[6];
    const float* veWih  = (const float*)d_in[7];
    const float* veWhh  = (const float*)d_in[8];
    const float* ve_bih = (const float*)d_in[9];
    const float* ve_bhh = (const float*)d_in[10];
    const float* deWih  = (const float*)d_in[11];
    const float* deWhh  = (const float*)d_in[12];
    const float* de_bih = (const float*)d_in[13];
    const float* de_bhh = (const float*)d_in[14];
    const float* fcW    = (const float*)d_in[15];
    const float* fcb    = (const float*)d_in[16];
    float* out = (float*)d_out;

    char* base = (char*)d_ws;
    // A buffers: 6 x 1024x1120 bf16 (pe0,pe1,ve0,ve1,dec0,dec1)
    ushort_t* Ape[2]  = {(ushort_t*)(base + 0UL * 2293760), (ushort_t*)(base + 1UL * 2293760)};
    ushort_t* Ave[2]  = {(ushort_t*)(base + 2UL * 2293760), (ushort_t*)(base + 3UL * 2293760)};
    ushort_t* Adec[2] = {(ushort_t*)(base + 4UL * 2293760), (ushort_t*)(base + 5UL * 2293760)};
    float* c_pe = (float*)(base + 13762560);
    float* c_ve = c_pe + 1048576;
    float* c_de = c_ve + 1048576;
    ushort_t* Wp    = (ushort_t*)(base + 26345472);   // 3 x 4096 x 1120
    float*    biasp = (float*)   (base + 53870592);   // 3 x 4096
    ushort_t* fcWb  = (ushort_t*)(base + 53919744);   // 75 x 1024
    ushort_t* pose_bf = (ushort_t*)(base + 54073344); // 1024x50x75
    ushort_t* vel_bf  = (ushort_t*)(base + 61753344); // 1024x49x75
    float*    accp    = (float*)   (base + 69279744); // 1024x75

    // zero: all 6 A buffers + c_pe + c_ve (contiguous)
    hipMemsetAsync(base, 0, 22151168, stream);

    pack_kernel<<<2048, 256, 0, stream>>>(peWih, peWhh, veWih, veWhh, deWih, deWhh,
                                          pe_bih, pe_bhh, ve_bih, ve_bhh, de_bih, de_bhh,
                                          fcW, Wp, biasp, fcWb);
    prep_kernel<<<2048, 256, 0, stream>>>(pose, fut, noise, pose_bf, vel_bf,
                                          Ape[0], Ave[0], Adec[0], accp, out);

    const ushort_t* Wpe = Wp;
    const ushort_t* Wve = Wp + 4587520;
    const ushort_t* Wde = Wp + 9175040;

    // --- encoders: dual launch (pe + ve) for t<49, single pe at t=49 ---
    for (int t = 0; t < 49; ++t) {
        StepArgs sa;
        sa.Ain[0] = Ape[t & 1];  sa.Aout[0] = Ape[(t + 1) & 1];
        sa.W[0] = Wpe; sa.bias[0] = biasp; sa.c[0] = c_pe;
        sa.xnext[0] = pose_bf + (size_t)(t + 1) * 75; sa.xstride[0] = 3750;
        sa.Ain[1] = Ave[t & 1];  sa.Aout[1] = Ave[(t + 1) & 1];
        sa.W[1] = Wve; sa.bias[1] = biasp + 4096; sa.c[1] = c_ve;
        sa.xnext[1] = (t < 48) ? (vel_bf + (size_t)(t + 1) * 75) : nullptr;
        sa.xstride[1] = 3675;
        lstm_step_kernel<<<512, 256, 0, stream>>>(sa);
    }
    {
        StepArgs sa;
        sa.Ain[0] = Ape[1]; sa.Aout[0] = Ape[0];
        sa.W[0] = Wpe; sa.bias[0] = biasp; sa.c[0] = c_pe;
        sa.xnext[0] = nullptr; sa.xstride[0] = 3750;
        sa.Ain[1] = sa.Ain[0]; sa.Aout[1] = sa.Aout[0];
        sa.W[1] = sa.W[0]; sa.bias[1] = sa.bias[0]; sa.c[1] = sa.c[0];
        sa.xnext[1] = nullptr; sa.xstride[1] = 3750;
        lstm_step_kernel<<<256, 256, 0, stream>>>(sa);
    }

    combine_kernel<<<4096, 256, 0, stream>>>(Ape[0], Ave[1], c_pe, c_ve, Adec[0], c_de);

    // --- decoder: 49 steps, fc feeds back into the next A_dec buffer ---
    for (int d = 0; d < 49; ++d) {
        StepArgs sa;
        sa.Ain[0] = Adec[d & 1]; sa.Aout[0] = Adec[(d + 1) & 1];
        sa.W[0] = Wde; sa.bias[0] = biasp + 8192; sa.c[0] = c_de;
        sa.xnext[0] = nullptr; sa.xstride[0] = 0;
        sa.Ain[1] = sa.Ain[0]; sa.Aout[1] = sa.Aout[0];
        sa.W[1] = sa.W[0]; sa.bias[1] = sa.bias[0]; sa.c[1] = sa.c[0];
        sa.xnext[1] = nullptr; sa.xstride[1] = 0;
        lstm_step_kernel<<<256, 256, 0, stream>>>(sa);
        fc_kernel<<<B_, 128, 0, stream>>>(Adec[(d + 1) & 1], Adec[(d + 1) & 1],
                                          fcWb, fcb, accp, out, d);
    }
}